// Round 6
// baseline (69.134 us; speedup 1.0000x reference)
//
#include <hip/hip_runtime.h>
#include <hip/hip_bf16.h>
#include <float.h>

// ChamferLoss: preds [B,N,3] f32, gts [B,N,3] f32 -> scalar f32
// R6: move dot products to the matrix pipe. P_ij = ||q_i - t_j||^2 realized as
// K=5 f16 MFMA: A_t = (tx,ty,tz,tn_hi,tn_lo), B_q = (-2qx,-2qy,-2qz,1,1);
// query norm added in f32 at the end. Target-norm f16 hi/lo split keeps
// per-pair error ~1e-5. One mfma_f32_32x32x16_f16 = 1024 pairs; per-pair VALU
// is 1 v_min. Prep kernel pre-packs target fragments into d_ws (1 MB).

#define BLK  256

typedef _Float16 f16x8 __attribute__((ext_vector_type(8)));
typedef float    f32x16 __attribute__((ext_vector_type(16)));
typedef float    f32x2 __attribute__((ext_vector_type(2)));
typedef float    f32x4 __attribute__((ext_vector_type(4)));

__device__ __forceinline__ unsigned int enc_f32(float f) {
    unsigned int u = __float_as_uint(f);
    return (u & 0x80000000u) ? ~u : (u | 0x80000000u);
}
__device__ __forceinline__ float dec_f32(unsigned int k) {
    return __uint_as_float((k & 0x80000000u) ? (k & 0x7FFFFFFFu) : ~k);
}

// ---------------- MFMA path ----------------

// Pack per-target fragment: 8 f16 = {tx,ty,tz,tn_hi,tn_lo,0,0,0}
__global__ __launch_bounds__(BLK) void chamfer_prep(
    const float* __restrict__ preds, const float* __restrict__ gts,
    uint4* __restrict__ frag, int N) {
    int gid = blockIdx.x * BLK + threadIdx.x;     // [0, 2*4*N)
    int dir = gid / (4 * N);
    int rem = gid - dir * 4 * N;
    int b = rem / N, i = rem - b * N;
    const float* src = (dir == 0) ? gts : preds;  // dir0: queries=preds, targets=gts
    const float* p = src + ((size_t)b * N + i) * 3;
    float x = p[0], y = p[1], z = p[2];
    _Float16 hx = (_Float16)x, hy = (_Float16)y, hz = (_Float16)z;
    float xr = (float)hx, yr = (float)hy, zr = (float)hz;
    float tn = xr * xr + yr * yr + zr * zr;
    _Float16 hi = (_Float16)tn;
    _Float16 lo = (_Float16)(tn - (float)hi);
    f16x8 f;
    f[0] = hx; f[1] = hy; f[2] = hz; f[3] = hi; f[4] = lo;
    f[5] = (_Float16)0.f; f[6] = (_Float16)0.f; f[7] = (_Float16)0.f;
    frag[gid] = __builtin_bit_cast(uint4, f);
}

// Block: 64 queries (2 strips of 32), 4 waves split the target tiles.
__global__ __launch_bounds__(BLK, 4) void chamfer_mfma(
    const float* __restrict__ preds, const float* __restrict__ gts,
    const uint4* __restrict__ frag, float* __restrict__ out, int N) {

    const int dir  = blockIdx.z;
    const int b    = blockIdx.y;
    const int tid  = threadIdx.x;
    const int wave = tid >> 6;
    const int lane = tid & 63;
    const int col  = lane & 31;
    const int qb   = blockIdx.x * 64;

    const float* Q = ((dir == 0) ? preds : gts) + (size_t)b * N * 3;
    const uint4* F = frag + ((size_t)dir * 4 + b) * N;

    // Build B fragments (queries) for the 2 strips; lanes>=32 carry k=8..15 -> 0
    f16x8 bf0, bf1;
    {
        const _Float16 c0 = (_Float16)0.f, c1 = (_Float16)1.f, cm2 = (_Float16)(-2.f);
        int q0 = qb + col, q1 = qb + 32 + col;
        float x0 = Q[q0*3], y0 = Q[q0*3+1], z0 = Q[q0*3+2];
        float x1 = Q[q1*3], y1 = Q[q1*3+1], z1 = Q[q1*3+2];
        bf0[0] = (_Float16)x0 * cm2; bf0[1] = (_Float16)y0 * cm2; bf0[2] = (_Float16)z0 * cm2;
        bf0[3] = c1; bf0[4] = c1; bf0[5] = c0; bf0[6] = c0; bf0[7] = c0;
        bf1[0] = (_Float16)x1 * cm2; bf1[1] = (_Float16)y1 * cm2; bf1[2] = (_Float16)z1 * cm2;
        bf1[3] = c1; bf1[4] = c1; bf1[5] = c0; bf1[6] = c0; bf1[7] = c0;
        if (lane >= 32) {
            #pragma unroll
            for (int j = 0; j < 8; ++j) { bf0[j] = c0; bf1[j] = c0; }
        }
    }

    f32x16 cz, rm0, rm1;
    #pragma unroll
    for (int j = 0; j < 16; ++j) { cz[j] = 0.f; rm0[j] = FLT_MAX; rm1[j] = FLT_MAX; }

    // A-fragment loads: lanes>=32's A elements feed k=8..15 whose B entries are
    // zero, so their loaded values are don't-care -> alias them to lane 0's
    // address (one extra 16B line).
    const int NT = (N >> 5) >> 2;                 // target tiles per wave (N/32/4)
    const uint4* base = F + (size_t)wave * 32 + ((lane < 32) ? col : 0);

    f16x8 curA = __builtin_bit_cast(f16x8, base[0]);
    #pragma unroll 2
    for (int it = 0; it < NT; ++it) {
        int nx = (it + 1 < NT) ? (it + 1) : it;
        uint4 nv = base[(size_t)nx * 128];        // next tile (4 tiles * 32 frags)
        f32x16 a0 = __builtin_amdgcn_mfma_f32_32x32x16_f16(curA, bf0, cz, 0, 0, 0);
        f32x16 a1 = __builtin_amdgcn_mfma_f32_32x32x16_f16(curA, bf1, cz, 0, 0, 0);
        #pragma unroll
        for (int j = 0; j < 16; ++j) {
            rm0[j] = fminf(rm0[j], a0[j]);
            rm1[j] = fminf(rm1[j], a1[j]);
        }
        curA = __builtin_bit_cast(f16x8, nv);
    }

    float m0 = rm0[0], m1 = rm1[0];
    #pragma unroll
    for (int j = 1; j < 16; ++j) { m0 = fminf(m0, rm0[j]); m1 = fminf(m1, rm1[j]); }

    __shared__ float lds[4][2][64];
    lds[wave][0][lane] = m0;
    lds[wave][1][lane] = m1;
    __syncthreads();

    if (tid < 64) {
        int s = tid >> 5, c = tid & 31;
        float m = FLT_MAX;
        #pragma unroll
        for (int w = 0; w < 4; ++w)
            m = fminf(m, fminf(lds[w][s][c], lds[w][s][c + 32]));
        int q = qb + tid;
        float x = Q[q*3], y = Q[q*3+1], z = Q[q*3+2];
        float xr = (float)(_Float16)x, yr = (float)(_Float16)y, zr = (float)(_Float16)z;
        float val = m + (xr * xr + yr * yr + zr * zr);
        #pragma unroll
        for (int off = 32; off > 0; off >>= 1)
            val += __shfl_down(val, off, 64);
        if (tid == 0) atomicAdd(out, val);
    }
}

// ---------------- Fallback path (R5) ----------------

#define SEG  32
#define Q    8

__device__ __forceinline__ float min3f(float a, float b, float c) {
    float r;
    asm("v_min3_f32 %0, %1, %2, %3" : "=v"(r) : "v"(a), "v"(b), "v"(c));
    return r;
}
__device__ __forceinline__ f32x2 pk_fma(f32x2 a, f32x2 b, f32x2 c) {
    f32x2 d;
    asm("v_pk_fma_f32 %0, %1, %2, %3" : "=v"(d) : "v"(a), "v"(b), "v"(c));
    return d;
}
__device__ __forceinline__ f32x2 pk_mul(f32x2 a, f32x2 b) {
    f32x2 d;
    asm("v_pk_mul_f32 %0, %1, %2" : "=v"(d) : "v"(a), "v"(b));
    return d;
}

__global__ __launch_bounds__(BLK, 4) void chamfer_min_kernel(
    const float* __restrict__ preds, const float* __restrict__ gts,
    unsigned int* __restrict__ keys, int N) {
    const int seg = blockIdx.z % SEG;
    const int dir = blockIdx.z / SEG;
    const int b   = blockIdx.y;
    const int tid = threadIdx.x;
    const int TT  = N / SEG;
    const float* Aq = dir == 0 ? preds : gts;
    const float* Bt = dir == 0 ? gts   : preds;
    const float* Ab = Aq + (size_t)b * N * 3;
    const float* Bb = Bt + (size_t)b * N * 3;
    __shared__ f32x2 shx[256], shy[256], shz[256];
    const int qbase = blockIdx.x * (BLK * Q);
    f32x2 a2x[Q], a2y[Q], a2z[Q];
    float an[Q]; bool vq[Q];
    #pragma unroll
    for (int q = 0; q < Q; ++q) {
        int idx = qbase + q * BLK + tid;
        vq[q] = idx < N;
        int ci = vq[q] ? idx : 0;
        float ax = Ab[ci*3], ay = Ab[ci*3+1], az = Ab[ci*3+2];
        a2x[q] = f32x2{-2.f*ax, -2.f*ax};
        a2y[q] = f32x2{-2.f*ay, -2.f*ay};
        a2z[q] = f32x2{-2.f*az, -2.f*az};
        an[q]  = ax*ax + ay*ay + az*az;
    }
    for (int p = tid; p < (TT >> 1); p += BLK) {
        int j0 = seg * TT + 2 * p;
        const f32x2* src = (const f32x2*)(Bb + (size_t)j0 * 3);
        f32x2 v01 = src[0], v23 = src[1], v45 = src[2];
        shx[p] = f32x2{v01.x, v23.y};
        shy[p] = f32x2{v01.y, v45.x};
        shz[p] = f32x2{v23.x, v45.y};
    }
    __syncthreads();
    float m[Q];
    #pragma unroll
    for (int q = 0; q < Q; ++q) m[q] = FLT_MAX;
    const f32x4* X4 = (const f32x4*)shx;
    const f32x4* Y4 = (const f32x4*)shy;
    const f32x4* Z4 = (const f32x4*)shz;
    const int KITER = TT >> 2;
    #pragma unroll 2
    for (int k = 0; k < KITER; ++k) {
        f32x4 X = X4[k], Y = Y4[k], Z = Z4[k];
        f32x2 w01 = pk_fma(Z.lo, Z.lo, pk_fma(Y.lo, Y.lo, pk_mul(X.lo, X.lo)));
        f32x2 w23 = pk_fma(Z.hi, Z.hi, pk_fma(Y.hi, Y.hi, pk_mul(X.hi, X.hi)));
        #pragma unroll
        for (int q = 0; q < Q; ++q) {
            f32x2 d0 = pk_fma(a2x[q], X.lo, pk_fma(a2y[q], Y.lo, pk_fma(a2z[q], Z.lo, w01)));
            f32x2 d1 = pk_fma(a2x[q], X.hi, pk_fma(a2y[q], Y.hi, pk_fma(a2z[q], Z.hi, w23)));
            m[q] = min3f(d0.x, d0.y, m[q]);
            m[q] = min3f(d1.x, d1.y, m[q]);
        }
    }
    #pragma unroll
    for (int q = 0; q < Q; ++q) {
        if (vq[q]) {
            int idx = qbase + q * BLK + tid;
            atomicMin(keys + ((size_t)(dir*4 + b) * N + idx), enc_f32(m[q] + an[q]));
        }
    }
}

__global__ __launch_bounds__(BLK) void chamfer_sum_kernel(
    const unsigned int* __restrict__ keys, float* __restrict__ out, int M) {
    __shared__ float psum[BLK / 64];
    int gid = blockIdx.x * BLK + threadIdx.x;
    int stride = gridDim.x * BLK;
    float s = 0.f;
    for (int i = gid; i < M; i += stride) s += dec_f32(keys[i]);
    for (int off = 32; off > 0; off >>= 1) s += __shfl_down(s, off, 64);
    if ((threadIdx.x & 63) == 0) psum[threadIdx.x >> 6] = s;
    __syncthreads();
    if (threadIdx.x == 0) {
        float t = 0.f;
        for (int w = 0; w < BLK / 64; ++w) t += psum[w];
        atomicAdd(out, t);
    }
}

extern "C" void kernel_launch(void* const* d_in, const int* in_sizes, int n_in,
                              void* d_out, int out_size, void* d_ws, size_t ws_size,
                              hipStream_t stream) {
    const float* preds = (const float*)d_in[0];
    const float* gts   = (const float*)d_in[1];
    float* out = (float*)d_out;

    const int B = 4, D = 3;
    const int N = in_sizes[0] / (B * D);   // 8192

    hipMemsetAsync(out, 0, sizeof(float) * out_size, stream);

    const size_t frag_bytes = (size_t)2 * B * N * sizeof(uint4);  // 1 MB
    if (ws_size >= frag_bytes && (N % 128) == 0) {
        uint4* frag = (uint4*)d_ws;
        int npts = 2 * B * N;
        chamfer_prep<<<npts / BLK, BLK, 0, stream>>>(preds, gts, frag, N);
        dim3 grid(N / 64, B, 2);
        chamfer_mfma<<<grid, BLK, 0, stream>>>(preds, gts, frag, out, N);
    } else {
        const size_t keys_bytes = (size_t)2 * B * N * sizeof(unsigned int);
        unsigned int* keys = (unsigned int*)d_ws;
        hipMemsetAsync(keys, 0xFF, keys_bytes, stream);
        dim3 grid((N + BLK * Q - 1) / (BLK * Q), B, 2 * SEG);
        chamfer_min_kernel<<<grid, BLK, 0, stream>>>(preds, gts, keys, N);
        chamfer_sum_kernel<<<64, BLK, 0, stream>>>(keys, out, 2 * B * N);
    }
}

// Round 7
// 37.593 us; speedup vs baseline: 1.8390x; 1.8390x over previous
//
#include <hip/hip_runtime.h>
#include <hip/hip_bf16.h>
#include <float.h>

// ChamferLoss: preds [B,N,3] f32, gts [B,N,3] f32 -> scalar f32
// R7: R6 MFMA formulation (proven correct) + depth-2 register prefetch
// (2-body unrolled loop, named regs) + 2 tiles/step with min3-foldable
// merge. P_ij via K=5 f16 MFMA: A_t=(tx,ty,tz,tn_hi,tn_lo), B_q=(-2qx,
// -2qy,-2qz,1,1); query norm added in f32 at epilogue.

#define BLK  256

typedef _Float16 f16x8 __attribute__((ext_vector_type(8)));
typedef float    f32x16 __attribute__((ext_vector_type(16)));
typedef float    f32x2 __attribute__((ext_vector_type(2)));
typedef float    f32x4 __attribute__((ext_vector_type(4)));

__device__ __forceinline__ unsigned int enc_f32(float f) {
    unsigned int u = __float_as_uint(f);
    return (u & 0x80000000u) ? ~u : (u | 0x80000000u);
}
__device__ __forceinline__ float dec_f32(unsigned int k) {
    return __uint_as_float((k & 0x80000000u) ? (k & 0x7FFFFFFFu) : ~k);
}

// ---------------- MFMA path ----------------

// Pack per-target fragment: 8 f16 = {tx,ty,tz,tn_hi,tn_lo,0,0,0}
__global__ __launch_bounds__(BLK) void chamfer_prep(
    const float* __restrict__ preds, const float* __restrict__ gts,
    uint4* __restrict__ frag, int N) {
    int gid = blockIdx.x * BLK + threadIdx.x;     // [0, 2*4*N)
    int dir = gid / (4 * N);
    int rem = gid - dir * 4 * N;
    int b = rem / N, i = rem - b * N;
    const float* src = (dir == 0) ? gts : preds;  // dir0: queries=preds
    const float* p = src + ((size_t)b * N + i) * 3;
    float x = p[0], y = p[1], z = p[2];
    _Float16 hx = (_Float16)x, hy = (_Float16)y, hz = (_Float16)z;
    float xr = (float)hx, yr = (float)hy, zr = (float)hz;
    float tn = xr * xr + yr * yr + zr * zr;
    _Float16 hi = (_Float16)tn;
    _Float16 lo = (_Float16)(tn - (float)hi);
    f16x8 f;
    f[0] = hx; f[1] = hy; f[2] = hz; f[3] = hi; f[4] = lo;
    f[5] = (_Float16)0.f; f[6] = (_Float16)0.f; f[7] = (_Float16)0.f;
    frag[gid] = __builtin_bit_cast(uint4, f);
}

#define MFMA16(A, B, C) __builtin_amdgcn_mfma_f32_32x32x16_f16((A), (B), (C), 0, 0, 0)

// Block: 64 queries (2 strips of 32), 4 waves split targets (N/4 each).
// Per step: 2 tiles (64 targets) x 2 strips = 4 MFMA + 32 foldable min3.
__global__ __launch_bounds__(BLK, 3) void chamfer_mfma(
    const float* __restrict__ preds, const float* __restrict__ gts,
    const uint4* __restrict__ frag, float* __restrict__ out, int N) {

    const int dir  = blockIdx.z;
    const int b    = blockIdx.y;
    const int tid  = threadIdx.x;
    const int wave = tid >> 6;
    const int lane = tid & 63;
    const int col  = lane & 31;
    const int qb   = blockIdx.x * 64;

    const float* Q = ((dir == 0) ? preds : gts) + (size_t)b * N * 3;
    const uint4* F = frag + ((size_t)dir * 4 + b) * N;

    // B fragments (queries) for the 2 strips; lanes>=32 (k=8..15) -> 0
    f16x8 bf0, bf1;
    {
        const _Float16 c0 = (_Float16)0.f, c1 = (_Float16)1.f, cm2 = (_Float16)(-2.f);
        int q0 = qb + col, q1 = qb + 32 + col;
        float x0 = Q[q0*3], y0 = Q[q0*3+1], z0 = Q[q0*3+2];
        float x1 = Q[q1*3], y1 = Q[q1*3+1], z1 = Q[q1*3+2];
        bf0[0] = (_Float16)x0 * cm2; bf0[1] = (_Float16)y0 * cm2; bf0[2] = (_Float16)z0 * cm2;
        bf0[3] = c1; bf0[4] = c1; bf0[5] = c0; bf0[6] = c0; bf0[7] = c0;
        bf1[0] = (_Float16)x1 * cm2; bf1[1] = (_Float16)y1 * cm2; bf1[2] = (_Float16)z1 * cm2;
        bf1[3] = c1; bf1[4] = c1; bf1[5] = c0; bf1[6] = c0; bf1[7] = c0;
        if (lane >= 32) {
            #pragma unroll
            for (int j = 0; j < 8; ++j) { bf0[j] = c0; bf1[j] = c0; }
        }
    }

    f32x16 cz, rm0, rm1;
    #pragma unroll
    for (int j = 0; j < 16; ++j) { cz[j] = 0.f; rm0[j] = FLT_MAX; rm1[j] = FLT_MAX; }

    // Wave owns N/4 targets = N/256 steps of 64 targets (2 tiles).
    // Lanes>=32 feed k=8..15 (B zero there) -> alias to frag 0 of the tile.
    const int NSTEP = N >> 8;                       // (N/4)/64
    const uint4* base = F + (size_t)wave * (N >> 2) + ((lane < 32) ? col : 0);

    uint4 pA0 = base[0],  pA1 = base[32];
    uint4 pB0 = base[64], pB1 = base[96];

    for (int s = 0; s < NSTEP; s += 2) {
        // ---- body A: compute step s, prefetch step s+2 ----
        {
            int ia = (s + 2 < NSTEP) ? (s + 2) : s;
            uint4 n0 = base[(size_t)ia * 64];
            uint4 n1 = base[(size_t)ia * 64 + 32];
            f16x8 a0 = __builtin_bit_cast(f16x8, pA0);
            f16x8 a1 = __builtin_bit_cast(f16x8, pA1);
            f32x16 x00 = MFMA16(a0, bf0, cz);
            f32x16 x01 = MFMA16(a1, bf0, cz);
            f32x16 x10 = MFMA16(a0, bf1, cz);
            f32x16 x11 = MFMA16(a1, bf1, cz);
            #pragma unroll
            for (int j = 0; j < 16; ++j) {
                rm0[j] = fminf(fminf(x00[j], x01[j]), rm0[j]);
                rm1[j] = fminf(fminf(x10[j], x11[j]), rm1[j]);
            }
            pA0 = n0; pA1 = n1;
        }
        // ---- body B: compute step s+1, prefetch step s+3 ----
        {
            int ib = (s + 3 < NSTEP) ? (s + 3) : (s + 1);
            uint4 n0 = base[(size_t)ib * 64];
            uint4 n1 = base[(size_t)ib * 64 + 32];
            f16x8 a0 = __builtin_bit_cast(f16x8, pB0);
            f16x8 a1 = __builtin_bit_cast(f16x8, pB1);
            f32x16 x00 = MFMA16(a0, bf0, cz);
            f32x16 x01 = MFMA16(a1, bf0, cz);
            f32x16 x10 = MFMA16(a0, bf1, cz);
            f32x16 x11 = MFMA16(a1, bf1, cz);
            #pragma unroll
            for (int j = 0; j < 16; ++j) {
                rm0[j] = fminf(fminf(x00[j], x01[j]), rm0[j]);
                rm1[j] = fminf(fminf(x10[j], x11[j]), rm1[j]);
            }
            pB0 = n0; pB1 = n1;
        }
    }

    float m0 = rm0[0], m1 = rm1[0];
    #pragma unroll
    for (int j = 1; j < 16; ++j) { m0 = fminf(m0, rm0[j]); m1 = fminf(m1, rm1[j]); }

    __shared__ float lds[4][2][64];
    lds[wave][0][lane] = m0;
    lds[wave][1][lane] = m1;
    __syncthreads();

    if (tid < 64) {
        int s = tid >> 5, c = tid & 31;
        float m = FLT_MAX;
        #pragma unroll
        for (int w = 0; w < 4; ++w)
            m = fminf(m, fminf(lds[w][s][c], lds[w][s][c + 32]));
        int q = qb + s * 32 + c;
        float x = Q[q*3], y = Q[q*3+1], z = Q[q*3+2];
        float xr = (float)(_Float16)x, yr = (float)(_Float16)y, zr = (float)(_Float16)z;
        float val = m + (xr * xr + yr * yr + zr * zr);
        #pragma unroll
        for (int off = 32; off > 0; off >>= 1)
            val += __shfl_down(val, off, 64);
        if (tid == 0) atomicAdd(out, val);
    }
}

// ---------------- Fallback path (R5 VALU version) ----------------

#define SEG  32
#define Q    8

__device__ __forceinline__ float min3f(float a, float b, float c) {
    float r;
    asm("v_min3_f32 %0, %1, %2, %3" : "=v"(r) : "v"(a), "v"(b), "v"(c));
    return r;
}
__device__ __forceinline__ f32x2 pk_fma(f32x2 a, f32x2 b, f32x2 c) {
    f32x2 d;
    asm("v_pk_fma_f32 %0, %1, %2, %3" : "=v"(d) : "v"(a), "v"(b), "v"(c));
    return d;
}
__device__ __forceinline__ f32x2 pk_mul(f32x2 a, f32x2 b) {
    f32x2 d;
    asm("v_pk_mul_f32 %0, %1, %2" : "=v"(d) : "v"(a), "v"(b));
    return d;
}

__global__ __launch_bounds__(BLK, 4) void chamfer_min_kernel(
    const float* __restrict__ preds, const float* __restrict__ gts,
    unsigned int* __restrict__ keys, int N) {
    const int seg = blockIdx.z % SEG;
    const int dir = blockIdx.z / SEG;
    const int b   = blockIdx.y;
    const int tid = threadIdx.x;
    const int TT  = N / SEG;
    const float* Aq = dir == 0 ? preds : gts;
    const float* Bt = dir == 0 ? gts   : preds;
    const float* Ab = Aq + (size_t)b * N * 3;
    const float* Bb = Bt + (size_t)b * N * 3;
    __shared__ f32x2 shx[256], shy[256], shz[256];
    const int qbase = blockIdx.x * (BLK * Q);
    f32x2 a2x[Q], a2y[Q], a2z[Q];
    float an[Q]; bool vq[Q];
    #pragma unroll
    for (int q = 0; q < Q; ++q) {
        int idx = qbase + q * BLK + tid;
        vq[q] = idx < N;
        int ci = vq[q] ? idx : 0;
        float ax = Ab[ci*3], ay = Ab[ci*3+1], az = Ab[ci*3+2];
        a2x[q] = f32x2{-2.f*ax, -2.f*ax};
        a2y[q] = f32x2{-2.f*ay, -2.f*ay};
        a2z[q] = f32x2{-2.f*az, -2.f*az};
        an[q]  = ax*ax + ay*ay + az*az;
    }
    for (int p = tid; p < (TT >> 1); p += BLK) {
        int j0 = seg * TT + 2 * p;
        const f32x2* src = (const f32x2*)(Bb + (size_t)j0 * 3);
        f32x2 v01 = src[0], v23 = src[1], v45 = src[2];
        shx[p] = f32x2{v01.x, v23.y};
        shy[p] = f32x2{v01.y, v45.x};
        shz[p] = f32x2{v23.x, v45.y};
    }
    __syncthreads();
    float m[Q];
    #pragma unroll
    for (int q = 0; q < Q; ++q) m[q] = FLT_MAX;
    const f32x4* X4 = (const f32x4*)shx;
    const f32x4* Y4 = (const f32x4*)shy;
    const f32x4* Z4 = (const f32x4*)shz;
    const int KITER = TT >> 2;
    #pragma unroll 2
    for (int k = 0; k < KITER; ++k) {
        f32x4 X = X4[k], Y = Y4[k], Z = Z4[k];
        f32x2 w01 = pk_fma(Z.lo, Z.lo, pk_fma(Y.lo, Y.lo, pk_mul(X.lo, X.lo)));
        f32x2 w23 = pk_fma(Z.hi, Z.hi, pk_fma(Y.hi, Y.hi, pk_mul(X.hi, X.hi)));
        #pragma unroll
        for (int q = 0; q < Q; ++q) {
            f32x2 d0 = pk_fma(a2x[q], X.lo, pk_fma(a2y[q], Y.lo, pk_fma(a2z[q], Z.lo, w01)));
            f32x2 d1 = pk_fma(a2x[q], X.hi, pk_fma(a2y[q], Y.hi, pk_fma(a2z[q], Z.hi, w23)));
            m[q] = min3f(d0.x, d0.y, m[q]);
            m[q] = min3f(d1.x, d1.y, m[q]);
        }
    }
    #pragma unroll
    for (int q = 0; q < Q; ++q) {
        if (vq[q]) {
            int idx = qbase + q * BLK + tid;
            atomicMin(keys + ((size_t)(dir*4 + b) * N + idx), enc_f32(m[q] + an[q]));
        }
    }
}

__global__ __launch_bounds__(BLK) void chamfer_sum_kernel(
    const unsigned int* __restrict__ keys, float* __restrict__ out, int M) {
    __shared__ float psum[BLK / 64];
    int gid = blockIdx.x * BLK + threadIdx.x;
    int stride = gridDim.x * BLK;
    float s = 0.f;
    for (int i = gid; i < M; i += stride) s += dec_f32(keys[i]);
    for (int off = 32; off > 0; off >>= 1) s += __shfl_down(s, off, 64);
    if ((threadIdx.x & 63) == 0) psum[threadIdx.x >> 6] = s;
    __syncthreads();
    if (threadIdx.x == 0) {
        float t = 0.f;
        for (int w = 0; w < BLK / 64; ++w) t += psum[w];
        atomicAdd(out, t);
    }
}

extern "C" void kernel_launch(void* const* d_in, const int* in_sizes, int n_in,
                              void* d_out, int out_size, void* d_ws, size_t ws_size,
                              hipStream_t stream) {
    const float* preds = (const float*)d_in[0];
    const float* gts   = (const float*)d_in[1];
    float* out = (float*)d_out;

    const int B = 4, D = 3;
    const int N = in_sizes[0] / (B * D);   // 8192

    hipMemsetAsync(out, 0, sizeof(float) * out_size, stream);

    const size_t frag_bytes = (size_t)2 * B * N * sizeof(uint4);  // 1 MB
    if (ws_size >= frag_bytes && (N % 256) == 0 && N >= 512) {
        uint4* frag = (uint4*)d_ws;
        int npts = 2 * B * N;
        chamfer_prep<<<npts / BLK, BLK, 0, stream>>>(preds, gts, frag, N);
        dim3 grid(N / 64, B, 2);
        chamfer_mfma<<<grid, BLK, 0, stream>>>(preds, gts, frag, out, N);
    } else {
        const size_t keys_bytes = (size_t)2 * B * N * sizeof(unsigned int);
        unsigned int* keys = (unsigned int*)d_ws;
        hipMemsetAsync(keys, 0xFF, keys_bytes, stream);
        dim3 grid((N + BLK * Q - 1) / (BLK * Q), B, 2 * SEG);
        chamfer_min_kernel<<<grid, BLK, 0, stream>>>(preds, gts, keys, N);
        chamfer_sum_kernel<<<64, BLK, 0, stream>>>(keys, out, 2 * B * N);
    }
}

// Round 8
// 37.492 us; speedup vs baseline: 1.8440x; 1.0027x over previous
//
#include <hip/hip_runtime.h>
#include <hip/hip_bf16.h>
#include <float.h>

// ChamferLoss: preds [B,N,3] f32, gts [B,N,3] f32 -> scalar f32
// R8: R7 skeleton, but register-disciplined: 1 tile x 2 strips per body
// (32 MFMA result regs live), pairwise min3 merge into 8-reg accumulators,
// depth-4 named-register prefetch with pointer-increment + immediate-offset
// addressing, __launch_bounds__(256,4) to keep everything in arch VGPRs
// (R6 counters showed ~6x VALU bloat from accvgpr moves + addr recompute).

#define BLK  256

typedef _Float16 f16x8 __attribute__((ext_vector_type(8)));
typedef float    f32x16 __attribute__((ext_vector_type(16)));
typedef float    f32x2 __attribute__((ext_vector_type(2)));
typedef float    f32x4 __attribute__((ext_vector_type(4)));

__device__ __forceinline__ unsigned int enc_f32(float f) {
    unsigned int u = __float_as_uint(f);
    return (u & 0x80000000u) ? ~u : (u | 0x80000000u);
}
__device__ __forceinline__ float dec_f32(unsigned int k) {
    return __uint_as_float((k & 0x80000000u) ? (k & 0x7FFFFFFFu) : ~k);
}

// ---------------- MFMA path ----------------

// Pack per-target fragment: 8 f16 = {tx,ty,tz,tn_hi,tn_lo,0,0,0}
__global__ __launch_bounds__(BLK) void chamfer_prep(
    const float* __restrict__ preds, const float* __restrict__ gts,
    uint4* __restrict__ frag, int N) {
    int gid = blockIdx.x * BLK + threadIdx.x;     // [0, 2*4*N)
    int dir = gid / (4 * N);
    int rem = gid - dir * 4 * N;
    int b = rem / N, i = rem - b * N;
    const float* src = (dir == 0) ? gts : preds;  // dir0: queries=preds
    const float* p = src + ((size_t)b * N + i) * 3;
    float x = p[0], y = p[1], z = p[2];
    _Float16 hx = (_Float16)x, hy = (_Float16)y, hz = (_Float16)z;
    float xr = (float)hx, yr = (float)hy, zr = (float)hz;
    float tn = xr * xr + yr * yr + zr * zr;
    _Float16 hi = (_Float16)tn;
    _Float16 lo = (_Float16)(tn - (float)hi);
    f16x8 f;
    f[0] = hx; f[1] = hy; f[2] = hz; f[3] = hi; f[4] = lo;
    f[5] = (_Float16)0.f; f[6] = (_Float16)0.f; f[7] = (_Float16)0.f;
    frag[gid] = __builtin_bit_cast(uint4, f);
}

#define MFMA16(A, B, C) __builtin_amdgcn_mfma_f32_32x32x16_f16((A), (B), (C), 0, 0, 0)

// Block: 64 queries (2 strips of 32), 4 waves split targets (N/4 each).
// Body: 1 tile (32 targets) x 2 strips = 2 MFMA + 16 min3.
__global__ __launch_bounds__(BLK, 4) void chamfer_mfma(
    const float* __restrict__ preds, const float* __restrict__ gts,
    const uint4* __restrict__ frag, float* __restrict__ out, int N) {

    const int dir  = blockIdx.z;
    const int b    = blockIdx.y;
    const int tid  = threadIdx.x;
    const int wave = tid >> 6;
    const int lane = tid & 63;
    const int col  = lane & 31;
    const int qb   = blockIdx.x * 64;

    const float* Q = ((dir == 0) ? preds : gts) + (size_t)b * N * 3;
    const uint4* F = frag + ((size_t)dir * 4 + b) * N;

    // B fragments (queries) for the 2 strips; lanes>=32 (k=8..15) -> 0
    f16x8 bf0, bf1;
    {
        const _Float16 c0 = (_Float16)0.f, c1 = (_Float16)1.f, cm2 = (_Float16)(-2.f);
        int q0 = qb + col, q1 = qb + 32 + col;
        float x0 = Q[q0*3], y0 = Q[q0*3+1], z0 = Q[q0*3+2];
        float x1 = Q[q1*3], y1 = Q[q1*3+1], z1 = Q[q1*3+2];
        bf0[0] = (_Float16)x0 * cm2; bf0[1] = (_Float16)y0 * cm2; bf0[2] = (_Float16)z0 * cm2;
        bf0[3] = c1; bf0[4] = c1; bf0[5] = c0; bf0[6] = c0; bf0[7] = c0;
        bf1[0] = (_Float16)x1 * cm2; bf1[1] = (_Float16)y1 * cm2; bf1[2] = (_Float16)z1 * cm2;
        bf1[3] = c1; bf1[4] = c1; bf1[5] = c0; bf1[6] = c0; bf1[7] = c0;
        if (lane >= 32) {
            #pragma unroll
            for (int j = 0; j < 8; ++j) { bf0[j] = c0; bf1[j] = c0; }
        }
    }

    f32x16 cz;
    float rm0[8], rm1[8];
    #pragma unroll
    for (int j = 0; j < 16; ++j) cz[j] = 0.f;
    #pragma unroll
    for (int j = 0; j < 8; ++j) { rm0[j] = FLT_MAX; rm1[j] = FLT_MAX; }

    // Wave owns N/4 targets; 4 bodies (128 targets) per iteration.
    // Lanes>=32 feed k=8..15 (B zero there) -> alias to tile frag 0.
    const int NIT = N >> 9;                        // (N/4)/128
    const uint4* p = F + (size_t)wave * (N >> 2) + ((lane < 32) ? col : 0);

    uint4 f0 = p[0], f1 = p[32], f2 = p[64], f3 = p[96];

#define BODY(FR, OFF)                                                   \
    {                                                                   \
        f16x8 a = __builtin_bit_cast(f16x8, FR);                        \
        f32x16 x0 = MFMA16(a, bf0, cz);                                 \
        f32x16 x1 = MFMA16(a, bf1, cz);                                 \
        _Pragma("unroll")                                               \
        for (int j = 0; j < 8; ++j) {                                   \
            rm0[j] = fminf(fminf(x0[2*j], x0[2*j+1]), rm0[j]);          \
            rm1[j] = fminf(fminf(x1[2*j], x1[2*j+1]), rm1[j]);          \
        }                                                               \
        FR = p[OFF];                                                    \
    }

    for (int it = 0; it < NIT; ++it) {
        BODY(f0, 128)
        BODY(f1, 160)
        BODY(f2, 192)
        BODY(f3, 224)
        p += 128;
    }
#undef BODY

    float m0 = rm0[0], m1 = rm1[0];
    #pragma unroll
    for (int j = 1; j < 8; ++j) { m0 = fminf(m0, rm0[j]); m1 = fminf(m1, rm1[j]); }

    __shared__ float lds[4][2][64];
    lds[wave][0][lane] = m0;
    lds[wave][1][lane] = m1;
    __syncthreads();

    if (tid < 64) {
        int s = tid >> 5, c = tid & 31;
        float m = FLT_MAX;
        #pragma unroll
        for (int w = 0; w < 4; ++w)
            m = fminf(m, fminf(lds[w][s][c], lds[w][s][c + 32]));
        int q = qb + s * 32 + c;
        float x = Q[q*3], y = Q[q*3+1], z = Q[q*3+2];
        float xr = (float)(_Float16)x, yr = (float)(_Float16)y, zr = (float)(_Float16)z;
        float val = m + (xr * xr + yr * yr + zr * zr);
        #pragma unroll
        for (int off = 32; off > 0; off >>= 1)
            val += __shfl_down(val, off, 64);
        if (tid == 0) atomicAdd(out, val);
    }
}

// ---------------- Fallback path (R5 VALU version) ----------------

#define SEG  32
#define Q    8

__device__ __forceinline__ float min3f(float a, float b, float c) {
    float r;
    asm("v_min3_f32 %0, %1, %2, %3" : "=v"(r) : "v"(a), "v"(b), "v"(c));
    return r;
}
__device__ __forceinline__ f32x2 pk_fma(f32x2 a, f32x2 b, f32x2 c) {
    f32x2 d;
    asm("v_pk_fma_f32 %0, %1, %2, %3" : "=v"(d) : "v"(a), "v"(b), "v"(c));
    return d;
}
__device__ __forceinline__ f32x2 pk_mul(f32x2 a, f32x2 b) {
    f32x2 d;
    asm("v_pk_mul_f32 %0, %1, %2" : "=v"(d) : "v"(a), "v"(b));
    return d;
}

__global__ __launch_bounds__(BLK, 4) void chamfer_min_kernel(
    const float* __restrict__ preds, const float* __restrict__ gts,
    unsigned int* __restrict__ keys, int N) {
    const int seg = blockIdx.z % SEG;
    const int dir = blockIdx.z / SEG;
    const int b   = blockIdx.y;
    const int tid = threadIdx.x;
    const int TT  = N / SEG;
    const float* Aq = dir == 0 ? preds : gts;
    const float* Bt = dir == 0 ? gts   : preds;
    const float* Ab = Aq + (size_t)b * N * 3;
    const float* Bb = Bt + (size_t)b * N * 3;
    __shared__ f32x2 shx[256], shy[256], shz[256];
    const int qbase = blockIdx.x * (BLK * Q);
    f32x2 a2x[Q], a2y[Q], a2z[Q];
    float an[Q]; bool vq[Q];
    #pragma unroll
    for (int q = 0; q < Q; ++q) {
        int idx = qbase + q * BLK + tid;
        vq[q] = idx < N;
        int ci = vq[q] ? idx : 0;
        float ax = Ab[ci*3], ay = Ab[ci*3+1], az = Ab[ci*3+2];
        a2x[q] = f32x2{-2.f*ax, -2.f*ax};
        a2y[q] = f32x2{-2.f*ay, -2.f*ay};
        a2z[q] = f32x2{-2.f*az, -2.f*az};
        an[q]  = ax*ax + ay*ay + az*az;
    }
    for (int p = tid; p < (TT >> 1); p += BLK) {
        int j0 = seg * TT + 2 * p;
        const f32x2* src = (const f32x2*)(Bb + (size_t)j0 * 3);
        f32x2 v01 = src[0], v23 = src[1], v45 = src[2];
        shx[p] = f32x2{v01.x, v23.y};
        shy[p] = f32x2{v01.y, v45.x};
        shz[p] = f32x2{v23.x, v45.y};
    }
    __syncthreads();
    float m[Q];
    #pragma unroll
    for (int q = 0; q < Q; ++q) m[q] = FLT_MAX;
    const f32x4* X4 = (const f32x4*)shx;
    const f32x4* Y4 = (const f32x4*)shy;
    const f32x4* Z4 = (const f32x4*)shz;
    const int KITER = TT >> 2;
    #pragma unroll 2
    for (int k = 0; k < KITER; ++k) {
        f32x4 X = X4[k], Y = Y4[k], Z = Z4[k];
        f32x2 w01 = pk_fma(Z.lo, Z.lo, pk_fma(Y.lo, Y.lo, pk_mul(X.lo, X.lo)));
        f32x2 w23 = pk_fma(Z.hi, Z.hi, pk_fma(Y.hi, Y.hi, pk_mul(X.hi, X.hi)));
        #pragma unroll
        for (int q = 0; q < Q; ++q) {
            f32x2 d0 = pk_fma(a2x[q], X.lo, pk_fma(a2y[q], Y.lo, pk_fma(a2z[q], Z.lo, w01)));
            f32x2 d1 = pk_fma(a2x[q], X.hi, pk_fma(a2y[q], Y.hi, pk_fma(a2z[q], Z.hi, w23)));
            m[q] = min3f(d0.x, d0.y, m[q]);
            m[q] = min3f(d1.x, d1.y, m[q]);
        }
    }
    #pragma unroll
    for (int q = 0; q < Q; ++q) {
        if (vq[q]) {
            int idx = qbase + q * BLK + tid;
            atomicMin(keys + ((size_t)(dir*4 + b) * N + idx), enc_f32(m[q] + an[q]));
        }
    }
}

__global__ __launch_bounds__(BLK) void chamfer_sum_kernel(
    const unsigned int* __restrict__ keys, float* __restrict__ out, int M) {
    __shared__ float psum[BLK / 64];
    int gid = blockIdx.x * BLK + threadIdx.x;
    int stride = gridDim.x * BLK;
    float s = 0.f;
    for (int i = gid; i < M; i += stride) s += dec_f32(keys[i]);
    for (int off = 32; off > 0; off >>= 1) s += __shfl_down(s, off, 64);
    if ((threadIdx.x & 63) == 0) psum[threadIdx.x >> 6] = s;
    __syncthreads();
    if (threadIdx.x == 0) {
        float t = 0.f;
        for (int w = 0; w < BLK / 64; ++w) t += psum[w];
        atomicAdd(out, t);
    }
}

extern "C" void kernel_launch(void* const* d_in, const int* in_sizes, int n_in,
                              void* d_out, int out_size, void* d_ws, size_t ws_size,
                              hipStream_t stream) {
    const float* preds = (const float*)d_in[0];
    const float* gts   = (const float*)d_in[1];
    float* out = (float*)d_out;

    const int B = 4, D = 3;
    const int N = in_sizes[0] / (B * D);   // 8192

    hipMemsetAsync(out, 0, sizeof(float) * out_size, stream);

    // frag buffer + 4 KB pad (deep prefetch reads past the last tile)
    const size_t frag_bytes = (size_t)2 * B * N * sizeof(uint4) + 4096;
    if (ws_size >= frag_bytes && (N % 512) == 0) {
        uint4* frag = (uint4*)d_ws;
        int npts = 2 * B * N;
        chamfer_prep<<<npts / BLK, BLK, 0, stream>>>(preds, gts, frag, N);
        dim3 grid(N / 64, B, 2);
        chamfer_mfma<<<grid, BLK, 0, stream>>>(preds, gts, frag, out, N);
    } else {
        const size_t keys_bytes = (size_t)2 * B * N * sizeof(unsigned int);
        unsigned int* keys = (unsigned int*)d_ws;
        hipMemsetAsync(keys, 0xFF, keys_bytes, stream);
        dim3 grid((N + BLK * Q - 1) / (BLK * Q), B, 2 * SEG);
        chamfer_min_kernel<<<grid, BLK, 0, stream>>>(preds, gts, keys, N);
        chamfer_sum_kernel<<<64, BLK, 0, stream>>>(keys, out, 2 * B * N);
    }
}

// Round 9
// 28.343 us; speedup vs baseline: 2.4392x; 1.3228x over previous
//
#include <hip/hip_runtime.h>
#include <hip/hip_bf16.h>
#include <float.h>

// ChamferLoss: preds [B,N,3] f32, gts [B,N,3] f32 -> scalar f32
// R9: R8 inner loop unchanged; replace the 1024 same-address atomicAdd(out)
// (suspected ~30-50cyc-serialized L2 RMW tail ~= 20us) with per-block
// partial stores + a 1-block deterministic reduce kernel. No atomics in the
// timed path; memset(out) dispatch dropped (reduce writes out directly).

#define BLK  256

typedef _Float16 f16x8 __attribute__((ext_vector_type(8)));
typedef float    f32x16 __attribute__((ext_vector_type(16)));
typedef float    f32x2 __attribute__((ext_vector_type(2)));
typedef float    f32x4 __attribute__((ext_vector_type(4)));

__device__ __forceinline__ unsigned int enc_f32(float f) {
    unsigned int u = __float_as_uint(f);
    return (u & 0x80000000u) ? ~u : (u | 0x80000000u);
}
__device__ __forceinline__ float dec_f32(unsigned int k) {
    return __uint_as_float((k & 0x80000000u) ? (k & 0x7FFFFFFFu) : ~k);
}

// ---------------- MFMA path ----------------

// Pack per-target fragment: 8 f16 = {tx,ty,tz,tn_hi,tn_lo,0,0,0}
__global__ __launch_bounds__(BLK) void chamfer_prep(
    const float* __restrict__ preds, const float* __restrict__ gts,
    uint4* __restrict__ frag, int N) {
    int gid = blockIdx.x * BLK + threadIdx.x;     // [0, 2*4*N)
    int dir = gid / (4 * N);
    int rem = gid - dir * 4 * N;
    int b = rem / N, i = rem - b * N;
    const float* src = (dir == 0) ? gts : preds;  // dir0: queries=preds
    const float* p = src + ((size_t)b * N + i) * 3;
    float x = p[0], y = p[1], z = p[2];
    _Float16 hx = (_Float16)x, hy = (_Float16)y, hz = (_Float16)z;
    float xr = (float)hx, yr = (float)hy, zr = (float)hz;
    float tn = xr * xr + yr * yr + zr * zr;
    _Float16 hi = (_Float16)tn;
    _Float16 lo = (_Float16)(tn - (float)hi);
    f16x8 f;
    f[0] = hx; f[1] = hy; f[2] = hz; f[3] = hi; f[4] = lo;
    f[5] = (_Float16)0.f; f[6] = (_Float16)0.f; f[7] = (_Float16)0.f;
    frag[gid] = __builtin_bit_cast(uint4, f);
}

#define MFMA16(A, B, C) __builtin_amdgcn_mfma_f32_32x32x16_f16((A), (B), (C), 0, 0, 0)

// Block: 64 queries (2 strips of 32), 4 waves split targets (N/4 each).
// Body: 1 tile (32 targets) x 2 strips = 2 MFMA + 16 min3.
// Epilogue: plain store of the block partial (no atomics).
__global__ __launch_bounds__(BLK, 4) void chamfer_mfma(
    const float* __restrict__ preds, const float* __restrict__ gts,
    const uint4* __restrict__ frag, float* __restrict__ partials, int N) {

    const int dir  = blockIdx.z;
    const int b    = blockIdx.y;
    const int tid  = threadIdx.x;
    const int wave = tid >> 6;
    const int lane = tid & 63;
    const int col  = lane & 31;
    const int qb   = blockIdx.x * 64;

    const float* Q = ((dir == 0) ? preds : gts) + (size_t)b * N * 3;
    const uint4* F = frag + ((size_t)dir * 4 + b) * N;

    // B fragments (queries) for the 2 strips; lanes>=32 (k=8..15) -> 0
    f16x8 bf0, bf1;
    {
        const _Float16 c0 = (_Float16)0.f, c1 = (_Float16)1.f, cm2 = (_Float16)(-2.f);
        int q0 = qb + col, q1 = qb + 32 + col;
        float x0 = Q[q0*3], y0 = Q[q0*3+1], z0 = Q[q0*3+2];
        float x1 = Q[q1*3], y1 = Q[q1*3+1], z1 = Q[q1*3+2];
        bf0[0] = (_Float16)x0 * cm2; bf0[1] = (_Float16)y0 * cm2; bf0[2] = (_Float16)z0 * cm2;
        bf0[3] = c1; bf0[4] = c1; bf0[5] = c0; bf0[6] = c0; bf0[7] = c0;
        bf1[0] = (_Float16)x1 * cm2; bf1[1] = (_Float16)y1 * cm2; bf1[2] = (_Float16)z1 * cm2;
        bf1[3] = c1; bf1[4] = c1; bf1[5] = c0; bf1[6] = c0; bf1[7] = c0;
        if (lane >= 32) {
            #pragma unroll
            for (int j = 0; j < 8; ++j) { bf0[j] = c0; bf1[j] = c0; }
        }
    }

    f32x16 cz;
    float rm0[8], rm1[8];
    #pragma unroll
    for (int j = 0; j < 16; ++j) cz[j] = 0.f;
    #pragma unroll
    for (int j = 0; j < 8; ++j) { rm0[j] = FLT_MAX; rm1[j] = FLT_MAX; }

    // Wave owns N/4 targets; 4 bodies (128 targets) per iteration.
    // Lanes>=32 feed k=8..15 (B zero there) -> alias to tile frag 0.
    const int NIT = N >> 9;                        // (N/4)/128
    const uint4* p = F + (size_t)wave * (N >> 2) + ((lane < 32) ? col : 0);

    uint4 f0 = p[0], f1 = p[32], f2 = p[64], f3 = p[96];

#define BODY(FR, OFF)                                                   \
    {                                                                   \
        f16x8 a = __builtin_bit_cast(f16x8, FR);                        \
        f32x16 x0 = MFMA16(a, bf0, cz);                                 \
        f32x16 x1 = MFMA16(a, bf1, cz);                                 \
        _Pragma("unroll")                                               \
        for (int j = 0; j < 8; ++j) {                                   \
            rm0[j] = fminf(fminf(x0[2*j], x0[2*j+1]), rm0[j]);          \
            rm1[j] = fminf(fminf(x1[2*j], x1[2*j+1]), rm1[j]);          \
        }                                                               \
        FR = p[OFF];                                                    \
    }

    for (int it = 0; it < NIT; ++it) {
        BODY(f0, 128)
        BODY(f1, 160)
        BODY(f2, 192)
        BODY(f3, 224)
        p += 128;
    }
#undef BODY

    float m0 = rm0[0], m1 = rm1[0];
    #pragma unroll
    for (int j = 1; j < 8; ++j) { m0 = fminf(m0, rm0[j]); m1 = fminf(m1, rm1[j]); }

    __shared__ float lds[4][2][64];
    lds[wave][0][lane] = m0;
    lds[wave][1][lane] = m1;
    __syncthreads();

    if (tid < 64) {
        int s = tid >> 5, c = tid & 31;
        float m = FLT_MAX;
        #pragma unroll
        for (int w = 0; w < 4; ++w)
            m = fminf(m, fminf(lds[w][s][c], lds[w][s][c + 32]));
        int q = qb + s * 32 + c;
        float x = Q[q*3], y = Q[q*3+1], z = Q[q*3+2];
        float xr = (float)(_Float16)x, yr = (float)(_Float16)y, zr = (float)(_Float16)z;
        float val = m + (xr * xr + yr * yr + zr * zr);
        #pragma unroll
        for (int off = 32; off > 0; off >>= 1)
            val += __shfl_down(val, off, 64);
        if (tid == 0) {
            int flat = blockIdx.x + gridDim.x * (blockIdx.y + 4 * blockIdx.z);
            partials[flat] = val;
        }
    }
}

// 1-block deterministic reduce: fixed per-thread slot sets, fixed tree.
__global__ __launch_bounds__(BLK) void chamfer_reduce(
    const float* __restrict__ partials, float* __restrict__ out,
    int nparts, int out_size) {
    const int tid = threadIdx.x;
    float s = 0.f;
    for (int i = tid; i < nparts; i += BLK) s += partials[i];
    __shared__ float psum[BLK / 64];
    #pragma unroll
    for (int off = 32; off > 0; off >>= 1) s += __shfl_down(s, off, 64);
    if ((tid & 63) == 0) psum[tid >> 6] = s;
    __syncthreads();
    if (tid == 0) {
        float t = 0.f;
        #pragma unroll
        for (int w = 0; w < BLK / 64; ++w) t += psum[w];
        out[0] = t;
    }
    // defensively zero any extra output elements (poisoned by harness)
    for (int i = 1 + tid; i < out_size; i += BLK) out[i] = 0.f;
}

// ---------------- Fallback path (R5 VALU version) ----------------

#define SEG  32
#define Q    8

__device__ __forceinline__ float min3f(float a, float b, float c) {
    float r;
    asm("v_min3_f32 %0, %1, %2, %3" : "=v"(r) : "v"(a), "v"(b), "v"(c));
    return r;
}
__device__ __forceinline__ f32x2 pk_fma(f32x2 a, f32x2 b, f32x2 c) {
    f32x2 d;
    asm("v_pk_fma_f32 %0, %1, %2, %3" : "=v"(d) : "v"(a), "v"(b), "v"(c));
    return d;
}
__device__ __forceinline__ f32x2 pk_mul(f32x2 a, f32x2 b) {
    f32x2 d;
    asm("v_pk_mul_f32 %0, %1, %2" : "=v"(d) : "v"(a), "v"(b));
    return d;
}

__global__ __launch_bounds__(BLK, 4) void chamfer_min_kernel(
    const float* __restrict__ preds, const float* __restrict__ gts,
    unsigned int* __restrict__ keys, int N) {
    const int seg = blockIdx.z % SEG;
    const int dir = blockIdx.z / SEG;
    const int b   = blockIdx.y;
    const int tid = threadIdx.x;
    const int TT  = N / SEG;
    const float* Aq = dir == 0 ? preds : gts;
    const float* Bt = dir == 0 ? gts   : preds;
    const float* Ab = Aq + (size_t)b * N * 3;
    const float* Bb = Bt + (size_t)b * N * 3;
    __shared__ f32x2 shx[256], shy[256], shz[256];
    const int qbase = blockIdx.x * (BLK * Q);
    f32x2 a2x[Q], a2y[Q], a2z[Q];
    float an[Q]; bool vq[Q];
    #pragma unroll
    for (int q = 0; q < Q; ++q) {
        int idx = qbase + q * BLK + tid;
        vq[q] = idx < N;
        int ci = vq[q] ? idx : 0;
        float ax = Ab[ci*3], ay = Ab[ci*3+1], az = Ab[ci*3+2];
        a2x[q] = f32x2{-2.f*ax, -2.f*ax};
        a2y[q] = f32x2{-2.f*ay, -2.f*ay};
        a2z[q] = f32x2{-2.f*az, -2.f*az};
        an[q]  = ax*ax + ay*ay + az*az;
    }
    for (int p = tid; p < (TT >> 1); p += BLK) {
        int j0 = seg * TT + 2 * p;
        const f32x2* src = (const f32x2*)(Bb + (size_t)j0 * 3);
        f32x2 v01 = src[0], v23 = src[1], v45 = src[2];
        shx[p] = f32x2{v01.x, v23.y};
        shy[p] = f32x2{v01.y, v45.x};
        shz[p] = f32x2{v23.x, v45.y};
    }
    __syncthreads();
    float m[Q];
    #pragma unroll
    for (int q = 0; q < Q; ++q) m[q] = FLT_MAX;
    const f32x4* X4 = (const f32x4*)shx;
    const f32x4* Y4 = (const f32x4*)shy;
    const f32x4* Z4 = (const f32x4*)shz;
    const int KITER = TT >> 2;
    #pragma unroll 2
    for (int k = 0; k < KITER; ++k) {
        f32x4 X = X4[k], Y = Y4[k], Z = Z4[k];
        f32x2 w01 = pk_fma(Z.lo, Z.lo, pk_fma(Y.lo, Y.lo, pk_mul(X.lo, X.lo)));
        f32x2 w23 = pk_fma(Z.hi, Z.hi, pk_fma(Y.hi, Y.hi, pk_mul(X.hi, X.hi)));
        #pragma unroll
        for (int q = 0; q < Q; ++q) {
            f32x2 d0 = pk_fma(a2x[q], X.lo, pk_fma(a2y[q], Y.lo, pk_fma(a2z[q], Z.lo, w01)));
            f32x2 d1 = pk_fma(a2x[q], X.hi, pk_fma(a2y[q], Y.hi, pk_fma(a2z[q], Z.hi, w23)));
            m[q] = min3f(d0.x, d0.y, m[q]);
            m[q] = min3f(d1.x, d1.y, m[q]);
        }
    }
    #pragma unroll
    for (int q = 0; q < Q; ++q) {
        if (vq[q]) {
            int idx = qbase + q * BLK + tid;
            atomicMin(keys + ((size_t)(dir*4 + b) * N + idx), enc_f32(m[q] + an[q]));
        }
    }
}

__global__ __launch_bounds__(BLK) void chamfer_sum_kernel(
    const unsigned int* __restrict__ keys, float* __restrict__ out, int M) {
    __shared__ float psum[BLK / 64];
    int gid = blockIdx.x * BLK + threadIdx.x;
    int stride = gridDim.x * BLK;
    float s = 0.f;
    for (int i = gid; i < M; i += stride) s += dec_f32(keys[i]);
    for (int off = 32; off > 0; off >>= 1) s += __shfl_down(s, off, 64);
    if ((threadIdx.x & 63) == 0) psum[threadIdx.x >> 6] = s;
    __syncthreads();
    if (threadIdx.x == 0) {
        float t = 0.f;
        for (int w = 0; w < BLK / 64; ++w) t += psum[w];
        atomicAdd(out, t);
    }
}

extern "C" void kernel_launch(void* const* d_in, const int* in_sizes, int n_in,
                              void* d_out, int out_size, void* d_ws, size_t ws_size,
                              hipStream_t stream) {
    const float* preds = (const float*)d_in[0];
    const float* gts   = (const float*)d_in[1];
    float* out = (float*)d_out;

    const int B = 4, D = 3;
    const int N = in_sizes[0] / (B * D);   // 8192

    // ws layout: [frag: 2*B*N uint4][4KB pad][partials: nblocks floats]
    const size_t frag_bytes = (size_t)2 * B * N * sizeof(uint4);
    const int    nblocks    = (N / 64) * B * 2;
    const size_t need = frag_bytes + 4096 + (size_t)nblocks * sizeof(float);

    if (ws_size >= need && (N % 512) == 0) {
        uint4* frag = (uint4*)d_ws;
        float* partials = (float*)((char*)d_ws + frag_bytes + 4096);
        int npts = 2 * B * N;
        chamfer_prep<<<npts / BLK, BLK, 0, stream>>>(preds, gts, frag, N);
        dim3 grid(N / 64, B, 2);
        chamfer_mfma<<<grid, BLK, 0, stream>>>(preds, gts, frag, partials, N);
        chamfer_reduce<<<1, BLK, 0, stream>>>(partials, out, nblocks, out_size);
    } else {
        hipMemsetAsync(out, 0, sizeof(float) * out_size, stream);
        const size_t keys_bytes = (size_t)2 * B * N * sizeof(unsigned int);
        unsigned int* keys = (unsigned int*)d_ws;
        hipMemsetAsync(keys, 0xFF, keys_bytes, stream);
        dim3 grid((N + BLK * Q - 1) / (BLK * Q), B, 2 * SEG);
        chamfer_min_kernel<<<grid, BLK, 0, stream>>>(preds, gts, keys, N);
        chamfer_sum_kernel<<<64, BLK, 0, stream>>>(keys, out, 2 * B * N);
    }
}